// Round 2
// 903.423 us; speedup vs baseline: 1.1466x; 1.1466x over previous
//
#include <hip/hip_runtime.h>
#include <hip/hip_bf16.h>

// E=8, C=4096, M=1024, H=4096, O=1024, fp32 in/out.
//   y   = relu(x @ fc1_w + fc1_b);  out = y @ fc2_w + fc2_b
// R4: same as R3 (256x256 8-phase bf16 MFMA GEMM, T2 XOR-swizzle, T5 setprio,
// T1 XCD-per-expert, counted vmcnt(4)) + compiler memory fences around raw
// s_barrier (m152 race-hardening: raw s_barrier has no compiler fence, so
// LLVM could hoist ds_read / global_load_lds across phase boundaries).

typedef __attribute__((ext_vector_type(8))) short short8;   // 8 bf16 = 4 VGPRs
typedef __attribute__((ext_vector_type(4))) float f32x4;

typedef const __attribute__((address_space(1))) void GV;
typedef __attribute__((address_space(3))) void LV;

// barrier with compiler-level memory fence on both sides (no extra instrs)
#define BAR()                                                                  \
    do {                                                                       \
        asm volatile("" ::: "memory");                                         \
        __builtin_amdgcn_s_barrier();                                          \
        asm volatile("" ::: "memory");                                         \
    } while (0)

__device__ inline ushort f2bf_rne(float f) {
    union { float f; unsigned u; } v; v.f = f;
    unsigned u = v.u;
    u += 0x7FFFu + ((u >> 16) & 1u);   // round-to-nearest-even
    return (ushort)(u >> 16);
}

// ---------------- elementwise fp32 -> bf16 convert, 8 elem/thread ----------------
__global__ __launch_bounds__(256) void convert_bf16(
    const float* __restrict__ in, ushort* __restrict__ out, long n) {
    long i = ((long)blockIdx.x * 256 + threadIdx.x) * 8;
    if (i + 7 >= n) return;
    float4 v0 = *(const float4*)&in[i];
    float4 v1 = *(const float4*)&in[i + 4];
    short8 o;
    o[0] = f2bf_rne(v0.x); o[1] = f2bf_rne(v0.y);
    o[2] = f2bf_rne(v0.z); o[3] = f2bf_rne(v0.w);
    o[4] = f2bf_rne(v1.x); o[5] = f2bf_rne(v1.y);
    o[6] = f2bf_rne(v1.z); o[7] = f2bf_rne(v1.w);
    *(short8*)&out[i] = o;
}

// ------------- [K,N] fp32 -> [N,K] bf16 tiled transpose, 16B stores -------------
__global__ __launch_bounds__(256) void transpose_convert(
    const float* __restrict__ in, ushort* __restrict__ out, int R, int Cn) {
    __shared__ float tile[64][65];
    const int e  = blockIdx.z;
    const float* ine  = in  + (size_t)e * R * Cn;
    ushort*      oute = out + (size_t)e * R * Cn;
    const int r0 = blockIdx.y * 64;
    const int c0 = blockIdx.x * 64;
    const int t  = threadIdx.x;
#pragma unroll
    for (int i = 0; i < 4; ++i) {
        int idx = i * 256 + t;
        int ir  = idx >> 4;
        int icc = (idx & 15) * 4;
        float4 v = *(const float4*)&ine[(size_t)(r0 + ir) * Cn + c0 + icc];
        tile[ir][icc + 0] = v.x; tile[ir][icc + 1] = v.y;
        tile[ir][icc + 2] = v.z; tile[ir][icc + 3] = v.w;
    }
    __syncthreads();
#pragma unroll
    for (int i = 0; i < 2; ++i) {
        int idx = i * 256 + t;
        int ic  = idx >> 3;
        int ir0 = (idx & 7) * 8;
        short8 o;
#pragma unroll
        for (int j = 0; j < 8; ++j) o[j] = f2bf_rne(tile[ir0 + j][ic]);
        *(short8*)&oute[(size_t)(c0 + ic) * R + r0 + ir0] = o;
    }
}

// ---------------- 256^2 8-phase bf16 GEMM, B^T input ----------------
// A: [E,4096,K] bf16 row-major; Bt: [E,N,K] bf16 row-major.
// Block: 512 thr = 8 waves (2M x 4N); per-wave out 128x64; BK=64.
// LDS: [buf2][mat2][half2][128x64 bf16] = 128 KiB, halves staged separately.
// Swizzle (T2, G4): element (r,c) of a half lives at r*64 + (c ^ ((r&7)<<3)).
// gload_lds writes linearly; source address is pre-inverse-swizzled (rule 21).

#define MFMA_Q(QM, QN)                                                         \
    do {                                                                       \
        _Pragma("unroll")                                                      \
        for (int kh = 0; kh < 2; ++kh)                                         \
            _Pragma("unroll")                                                  \
            for (int mf = 0; mf < 4; ++mf)                                     \
                _Pragma("unroll")                                              \
                for (int nf = 0; nf < 2; ++nf)                                 \
                    acc[(QM) * 4 + mf][(QN) * 2 + nf] =                        \
                        __builtin_amdgcn_mfma_f32_16x16x32_bf16(               \
                            a[(QM) * 4 + mf][kh], b[nf][kh],                   \
                            acc[(QM) * 4 + mf][(QN) * 2 + nf], 0, 0, 0);       \
    } while (0)

// Stage one 128x64 half-tile slice: 2 x global_load_lds(16B) per thread.
#define STAGE(P0, P1_, HOFF, LBASE, TG)                                        \
    do {                                                                       \
        const int _tg = (TG);                                                  \
        if (_tg < NTt) {                                                       \
            const size_t _k = (size_t)_tg * 64;                                \
            __builtin_amdgcn_global_load_lds((GV*)((P0) + (HOFF) + _k),        \
                (LV*)&smem[(LBASE) + d0], 16, 0, 0);                           \
            __builtin_amdgcn_global_load_lds((GV*)((P1_) + (HOFF) + _k),       \
                (LV*)&smem[(LBASE) + d1], 16, 0, 0);                           \
        }                                                                      \
    } while (0)

template <bool RELU_BF16_OUT, int MT, int NTILES, int K, int N>
__global__ __launch_bounds__(512, 2) void gemm8p(
    const ushort* __restrict__ A, const ushort* __restrict__ Bt,
    const float* __restrict__ bias, void* __restrict__ out) {
    __shared__ ushort smem[65536];          // 128 KiB
    constexpr int NTt = K / 64;             // K-tiles
    constexpr int STC = NTILES / 4;         // supertile columns

    // T1: pid%8 -> XCD; each XCD owns one expert (tiles/expert == nwg/8).
    const int pid = blockIdx.x;
    const int e   = pid & 7;
    const int idx = pid >> 3;
    const int s  = idx >> 4, wi = idx & 15; // 4x4 supertiles
    const int by = (s / STC) * 4 + (wi >> 2);
    const int bx = (s % STC) * 4 + (wi & 3);
    const int m0 = by * 256, n0 = bx * 256;

    const ushort* Ae = A  + (size_t)e * 4096 * K;
    const ushort* Be = Bt + (size_t)e * N * K;
    const float*  be = bias + (size_t)e * N;

    const int t    = threadIdx.x;
    const int w    = t >> 6, l = t & 63;
    const int wm   = w >> 2;                // wave_m in {0,1}
    const int wn   = w & 3;                 // wave_n in {0..3}
    const int lrow = l & 15, q = l >> 4;
    const int swz  = (lrow & 7) << 3;       // read-side XOR (elements)

    // staging geometry: thread slice i=0/1 -> row r, pre-inverse-swizzled col c
    const int r0s = w * 16 + (l >> 3);
    const int r1s = r0s + 8;
    const int c0s = ((l & 7) ^ (r0s & 7)) << 3;
    const int c1s = ((l & 7) ^ (r1s & 7)) << 3;
    const int d0  = w * 1024 + l * 8;       // linear LDS dest (elements)
    const int d1  = d0 + 512;

    const ushort* pa0 = Ae + (size_t)(m0 + r0s) * K + c0s;
    const ushort* pa1 = Ae + (size_t)(m0 + r1s) * K + c1s;
    const ushort* pb0 = Be + (size_t)(n0 + r0s) * K + c0s;
    const ushort* pb1 = Be + (size_t)(n0 + r1s) * K + c1s;

    // bias first + drain, so the vmem queue holds ONLY staging loads
    float bv[4];
#pragma unroll
    for (int nf = 0; nf < 4; ++nf) bv[nf] = be[n0 + wn * 64 + nf * 16 + lrow];
    asm volatile("s_waitcnt vmcnt(0)" ::: "memory");

    // prologue: A(0),B(0) + A(1); wait tile0 (8 loads), keep A(1) in flight
    STAGE(pa0, pa1, (size_t)0,       0,             0);   // A h0 t0
    STAGE(pa0, pa1, (size_t)128 * K, 8192,          0);   // A h1 t0
    STAGE(pb0, pb1, (size_t)0,       16384,         0);   // B h0 t0
    STAGE(pb0, pb1, (size_t)128 * K, 16384 + 8192,  0);   // B h1 t0
    STAGE(pa0, pa1, (size_t)0,       32768,         1);   // A h0 t1
    STAGE(pa0, pa1, (size_t)128 * K, 32768 + 8192,  1);   // A h1 t1
    asm volatile("s_waitcnt vmcnt(4)" ::: "memory");
    BAR();

    short8 a[8][2], b[2][2];
    f32x4 acc[8][4] = {};

    for (int ti = 0; ti < NTt; ++ti) {
        const int buf  = ti & 1;
        const int obuf = buf ^ 1;
        const ushort* Ab = &smem[buf * 32768 + wm * 8192];
        const ushort* Bb = &smem[buf * 32768 + 16384 + (wn >> 1) * 8192 +
                                 (wn & 1) * 4096];

        // ---- P1: read a[0..3]+b(qn0); stage B h0(t+1)->obuf; MFMA Q(0,0) ----
#pragma unroll
        for (int mf = 0; mf < 4; ++mf)
#pragma unroll
            for (int kh = 0; kh < 2; ++kh)
                a[mf][kh] = *(const short8*)
                    &Ab[(mf * 16 + lrow) * 64 + ((kh * 32 + q * 8) ^ swz)];
#pragma unroll
        for (int nf = 0; nf < 2; ++nf)
#pragma unroll
            for (int kh = 0; kh < 2; ++kh)
                b[nf][kh] = *(const short8*)
                    &Bb[(nf * 16 + lrow) * 64 + ((kh * 32 + q * 8) ^ swz)];
        STAGE(pb0, pb1, (size_t)0, obuf * 32768 + 16384, ti + 1);
        BAR();
        __builtin_amdgcn_s_setprio(1);
        MFMA_Q(0, 0);
        __builtin_amdgcn_s_setprio(0);
        BAR();

        // ---- P2: read a[4..7]; stage B h1(t+1)->obuf; MFMA Q(1,0) ----
#pragma unroll
        for (int mf = 0; mf < 4; ++mf)
#pragma unroll
            for (int kh = 0; kh < 2; ++kh)
                a[4 + mf][kh] = *(const short8*)
                    &Ab[((4 + mf) * 16 + lrow) * 64 + ((kh * 32 + q * 8) ^ swz)];
        STAGE(pb0, pb1, (size_t)128 * K, obuf * 32768 + 16384 + 8192, ti + 1);
        BAR();
        __builtin_amdgcn_s_setprio(1);
        MFMA_Q(1, 0);
        __builtin_amdgcn_s_setprio(0);
        BAR();

        // ---- P3: read b(qn1); A fully consumed -> stage A h0(t+2)->buf ----
#pragma unroll
        for (int nf = 0; nf < 2; ++nf)
#pragma unroll
            for (int kh = 0; kh < 2; ++kh)
                b[nf][kh] = *(const short8*)
                    &Bb[((2 + nf) * 16 + lrow) * 64 + ((kh * 32 + q * 8) ^ swz)];
        STAGE(pa0, pa1, (size_t)0, buf * 32768, ti + 2);
        BAR();
        __builtin_amdgcn_s_setprio(1);
        MFMA_Q(1, 1);
        __builtin_amdgcn_s_setprio(0);
        BAR();

        // ---- P4: stage A h1(t+2)->buf; MFMA Q(0,1); counted vmcnt ----
        STAGE(pa0, pa1, (size_t)128 * K, buf * 32768 + 8192, ti + 2);
        BAR();
        __builtin_amdgcn_s_setprio(1);
        MFMA_Q(0, 1);
        __builtin_amdgcn_s_setprio(0);
        if (ti < NTt - 2) {
            asm volatile("s_waitcnt vmcnt(4)" ::: "memory");   // t+1 resident
        } else if (ti == NTt - 2) {
            asm volatile("s_waitcnt vmcnt(0)" ::: "memory");   // tail drain
        }
        BAR();
    }

    // epilogue: C/D layout col=lane&15, row=quad*4+reg [m89/m91 verified]
    const size_t obase = (size_t)e * 4096 * N;
#pragma unroll
    for (int mf = 0; mf < 8; ++mf) {
#pragma unroll
        for (int nf = 0; nf < 4; ++nf) {
            const int gn = n0 + wn * 64 + nf * 16 + lrow;
#pragma unroll
            for (int rr = 0; rr < 4; ++rr) {
                const int gm = m0 + wm * 128 + mf * 16 + q * 4 + rr;
                float v = acc[mf][nf][rr] + bv[nf];
                if (RELU_BF16_OUT) {
                    v = fmaxf(v, 0.f);
                    ((ushort*)out)[obase + (size_t)gm * N + gn] = f2bf_rne(v);
                } else {
                    ((float*)out)[obase + (size_t)gm * N + gn] = v;
                }
            }
        }
    }
}

extern "C" void kernel_launch(void* const* d_in, const int* in_sizes, int n_in,
                              void* d_out, int out_size, void* d_ws, size_t ws_size,
                              hipStream_t stream) {
    const int E = 8, C = 4096, M = 1024, H = 4096, O = 1024;
    const float* x  = (const float*)d_in[0];
    const float* w1 = (const float*)d_in[1];
    const float* b1 = (const float*)d_in[2];
    const float* w2 = (const float*)d_in[3];
    const float* b2 = (const float*)d_in[4];
    float* out = (float*)d_out;

    // workspace: [x_bf 67MB][w1t 67MB][y 268MB]; w2t aliases w1t (used after GEMM1)
    ushort* x_bf = (ushort*)d_ws;                       // E*C*M
    ushort* w1t  = x_bf + (size_t)E * C * M;            // E*H*M
    ushort* w2t  = w1t;                                 // E*O*H (alias, after GEMM1)
    ushort* y_bf = w1t + (size_t)E * M * H;             // E*C*H

    const long nx = (long)E * C * M;
    convert_bf16<<<(nx / 8 + 255) / 256, 256, 0, stream>>>(x, x_bf, nx);
    transpose_convert<<<dim3(H / 64, M / 64, E), 256, 0, stream>>>(w1, w1t, M, H);
    // GEMM1: [E,4096,1024] @ [E,4096,1024]^T -> y [E,4096,4096] bf16, relu+bias
    gemm8p<true, 16, 16, 1024, 4096><<<16 * 16 * 8, 512, 0, stream>>>(
        x_bf, w1t, b1, (void*)y_bf);
    transpose_convert<<<dim3(O / 64, H / 64, E), 256, 0, stream>>>(w2, w2t, H, O);
    // GEMM2: [E,4096,4096] @ [E,1024,4096]^T -> out [E,4096,1024] fp32, bias
    gemm8p<false, 16, 4, 4096, 1024><<<16 * 4 * 8, 512, 0, stream>>>(
        y_bf, w2t, b2, (void*)out);
}

// Round 3
// 878.076 us; speedup vs baseline: 1.1797x; 1.0289x over previous
//
#include <hip/hip_runtime.h>
#include <hip/hip_bf16.h>

// E=8, C=4096, M=1024, H=4096, O=1024, fp32 in/out.
//   y   = relu(x @ fc1_w + fc1_b);  out = y @ fc2_w + fc2_b
// R5: R4 (256x256 8-phase, T1/T2/T5, counted vmcnt) +
//  (a) dense MFMA bursts: BAR -> asm lgkmcnt(0) -> sched_barrier(0) -> 16 MFMA
//      (m201/m214 verified pattern; compiler's interleaved waits defeated bursts)
//  (b) balanced LDS reads 4/8/4/8 per phase (was 12/8/4/0; P1 was LDS-bound):
//      next tile's a(0..3) prefetched into tile t's P4 under vmcnt(6) pre-wait,
//      register-neutral via CUR/HI role rotation + 2-tile static unroll.

typedef __attribute__((ext_vector_type(8))) short short8;   // 8 bf16 = 4 VGPRs
typedef __attribute__((ext_vector_type(4))) float f32x4;

typedef const __attribute__((address_space(1))) void GV;
typedef __attribute__((address_space(3))) void LV;

// barrier with compiler-level memory fence on both sides (no extra instrs)
#define BAR()                                                                  \
    do {                                                                       \
        asm volatile("" ::: "memory");                                         \
        __builtin_amdgcn_s_barrier();                                          \
        asm volatile("" ::: "memory");                                         \
    } while (0)

__device__ inline ushort f2bf_rne(float f) {
    union { float f; unsigned u; } v; v.f = f;
    unsigned u = v.u;
    u += 0x7FFFu + ((u >> 16) & 1u);   // round-to-nearest-even
    return (ushort)(u >> 16);
}

// ---------------- elementwise fp32 -> bf16 convert, 8 elem/thread ----------------
__global__ __launch_bounds__(256) void convert_bf16(
    const float* __restrict__ in, ushort* __restrict__ out, long n) {
    long i = ((long)blockIdx.x * 256 + threadIdx.x) * 8;
    if (i + 7 >= n) return;
    float4 v0 = *(const float4*)&in[i];
    float4 v1 = *(const float4*)&in[i + 4];
    short8 o;
    o[0] = f2bf_rne(v0.x); o[1] = f2bf_rne(v0.y);
    o[2] = f2bf_rne(v0.z); o[3] = f2bf_rne(v0.w);
    o[4] = f2bf_rne(v1.x); o[5] = f2bf_rne(v1.y);
    o[6] = f2bf_rne(v1.z); o[7] = f2bf_rne(v1.w);
    *(short8*)&out[i] = o;
}

// ------------- [K,N] fp32 -> [N,K] bf16 tiled transpose, 16B stores -------------
__global__ __launch_bounds__(256) void transpose_convert(
    const float* __restrict__ in, ushort* __restrict__ out, int R, int Cn) {
    __shared__ float tile[64][65];
    const int e  = blockIdx.z;
    const float* ine  = in  + (size_t)e * R * Cn;
    ushort*      oute = out + (size_t)e * R * Cn;
    const int r0 = blockIdx.y * 64;
    const int c0 = blockIdx.x * 64;
    const int t  = threadIdx.x;
#pragma unroll
    for (int i = 0; i < 4; ++i) {
        int idx = i * 256 + t;
        int ir  = idx >> 4;
        int icc = (idx & 15) * 4;
        float4 v = *(const float4*)&ine[(size_t)(r0 + ir) * Cn + c0 + icc];
        tile[ir][icc + 0] = v.x; tile[ir][icc + 1] = v.y;
        tile[ir][icc + 2] = v.z; tile[ir][icc + 3] = v.w;
    }
    __syncthreads();
#pragma unroll
    for (int i = 0; i < 2; ++i) {
        int idx = i * 256 + t;
        int ic  = idx >> 3;
        int ir0 = (idx & 7) * 8;
        short8 o;
#pragma unroll
        for (int j = 0; j < 8; ++j) o[j] = f2bf_rne(tile[ir0 + j][ic]);
        *(short8*)&oute[(size_t)(c0 + ic) * R + r0 + ir0] = o;
    }
}

// ---------------- 256^2 8-phase bf16 GEMM, B^T input ----------------
// A: [E,4096,K] bf16 row-major; Bt: [E,N,K] bf16 row-major.
// Block: 512 thr = 8 waves (2M x 4N); per-wave out 128x64; BK=64.
// LDS: [buf2][mat2][half2][128x64 bf16] = 128 KiB.
// Swizzle (T2, G4): element (r,c) of a half lives at r*64 + (c ^ ((r&7)<<3)).
// gload_lds writes linearly; source address is pre-inverse-swizzled (rule 21).

#define MFMA_BURST(AARR, ABASE, QN)                                            \
    do {                                                                       \
        _Pragma("unroll")                                                      \
        for (int kh = 0; kh < 2; ++kh)                                         \
            _Pragma("unroll")                                                  \
            for (int mf = 0; mf < 4; ++mf)                                     \
                _Pragma("unroll")                                              \
                for (int nf = 0; nf < 2; ++nf)                                 \
                    acc[(ABASE) + mf][(QN) * 2 + nf] =                         \
                        __builtin_amdgcn_mfma_f32_16x16x32_bf16(               \
                            AARR[mf][kh], b[nf][kh],                           \
                            acc[(ABASE) + mf][(QN) * 2 + nf], 0, 0, 0);        \
    } while (0)

// Stage one 128x64 half-tile slice: 2 x global_load_lds(16B) per thread.
#define STAGE(P0, P1_, HOFF, LBASE, TG)                                        \
    do {                                                                       \
        const int _tg = (TG);                                                  \
        if (_tg < NTt) {                                                       \
            const size_t _k = (size_t)_tg * 64;                                \
            __builtin_amdgcn_global_load_lds((GV*)((P0) + (HOFF) + _k),        \
                (LV*)&smem[(LBASE) + d0], 16, 0, 0);                           \
            __builtin_amdgcn_global_load_lds((GV*)((P1_) + (HOFF) + _k),       \
                (LV*)&smem[(LBASE) + d1], 16, 0, 0);                           \
        }                                                                      \
    } while (0)

// One K-tile = 4 phases. CUR holds a(0..3) (read at prev tile's P4); HI gets
// a(4..7) at P2, is dead after P3's burst, then receives NEXT tile's a(0..3)
// at P4 (becoming next tile's CUR). PBUF is a literal 0/1.
#define TILE_BODY(TI, CUR, HI, PBUF)                                           \
  do {                                                                         \
    const int ti_ = (TI);                                                      \
    const ushort* Ab_  = &smem[(PBUF) * 32768 + wm * 8192];                    \
    const ushort* Bb_  = &smem[(PBUF) * 32768 + 16384 + (wn >> 1) * 8192 +     \
                               (wn & 1) * 4096];                               \
    const ushort* AbN_ = &smem[((PBUF) ^ 1) * 32768 + wm * 8192];              \
    /* ---- P1: read b(0,1); stage B h0(t+1)->obuf; MFMA Q(0,0) ---- */        \
    _Pragma("unroll")                                                          \
    for (int nf = 0; nf < 2; ++nf)                                             \
        _Pragma("unroll")                                                      \
        for (int kh = 0; kh < 2; ++kh)                                         \
            b[nf][kh] = *(const short8*)                                       \
                &Bb_[(nf * 16 + lrow) * 64 + ((kh * 32 + q * 8) ^ swz)];       \
    STAGE(pb0, pb1, (size_t)0, ((PBUF) ^ 1) * 32768 + 16384, ti_ + 1);         \
    BAR();                                                                     \
    asm volatile("s_waitcnt lgkmcnt(0)" ::: "memory");                         \
    __builtin_amdgcn_sched_barrier(0);                                         \
    __builtin_amdgcn_s_setprio(1);                                             \
    MFMA_BURST(CUR, 0, 0);                                                     \
    __builtin_amdgcn_s_setprio(0);                                             \
    BAR();                                                                     \
    /* ---- P2: read HI=a(4..7); stage B h1(t+1)->obuf; MFMA Q(1,0) ---- */    \
    _Pragma("unroll")                                                          \
    for (int mf = 0; mf < 4; ++mf)                                             \
        _Pragma("unroll")                                                      \
        for (int kh = 0; kh < 2; ++kh)                                         \
            HI[mf][kh] = *(const short8*)                                      \
                &Ab_[((4 + mf) * 16 + lrow) * 64 + ((kh * 32 + q * 8) ^ swz)]; \
    STAGE(pb0, pb1, (size_t)128 * K, ((PBUF) ^ 1) * 32768 + 16384 + 8192,      \
          ti_ + 1);                                                            \
    BAR();                                                                     \
    asm volatile("s_waitcnt lgkmcnt(0)" ::: "memory");                         \
    __builtin_amdgcn_sched_barrier(0);                                         \
    __builtin_amdgcn_s_setprio(1);                                             \
    MFMA_BURST(HI, 4, 0);                                                      \
    __builtin_amdgcn_s_setprio(0);                                             \
    BAR();                                                                     \
    /* ---- P3: read b(2,3); stage A h0(t+2)->PBUF; MFMA Q(1,1) ---- */        \
    _Pragma("unroll")                                                          \
    for (int nf = 0; nf < 2; ++nf)                                             \
        _Pragma("unroll")                                                      \
        for (int kh = 0; kh < 2; ++kh)                                         \
            b[nf][kh] = *(const short8*)                                       \
                &Bb_[((2 + nf) * 16 + lrow) * 64 + ((kh * 32 + q * 8) ^ swz)]; \
    STAGE(pa0, pa1, (size_t)0, (PBUF) * 32768, ti_ + 2);                       \
    BAR();                                                                     \
    asm volatile("s_waitcnt lgkmcnt(0)" ::: "memory");                         \
    __builtin_amdgcn_sched_barrier(0);                                         \
    __builtin_amdgcn_s_setprio(1);                                             \
    MFMA_BURST(HI, 4, 1);                                                      \
    __builtin_amdgcn_s_setprio(0);                                             \
    BAR();                                                                     \
    /* ---- P4: prefetch next a(0..3)->HI (A(t+1) resident per vmcnt);         \
            stage A h1(t+2)->PBUF; MFMA Q(0,1); counted end-wait ---- */       \
    if (ti_ + 1 < NTt) {                                                       \
        if (ti_ < NTt - 2)                                                     \
            asm volatile("s_waitcnt vmcnt(6)" ::: "memory");                   \
        else                                                                   \
            asm volatile("s_waitcnt vmcnt(4)" ::: "memory");                   \
        _Pragma("unroll")                                                      \
        for (int mf = 0; mf < 4; ++mf)                                         \
            _Pragma("unroll")                                                  \
            for (int kh = 0; kh < 2; ++kh)                                     \
                HI[mf][kh] = *(const short8*)                                  \
                    &AbN_[(mf * 16 + lrow) * 64 + ((kh * 32 + q * 8) ^ swz)];  \
    }                                                                          \
    STAGE(pa0, pa1, (size_t)128 * K, (PBUF) * 32768 + 8192, ti_ + 2);          \
    BAR();                                                                     \
    asm volatile("s_waitcnt lgkmcnt(0)" ::: "memory");                         \
    __builtin_amdgcn_sched_barrier(0);                                         \
    __builtin_amdgcn_s_setprio(1);                                             \
    MFMA_BURST(CUR, 0, 1);                                                     \
    __builtin_amdgcn_s_setprio(0);                                             \
    if (ti_ < NTt - 2)                                                         \
        asm volatile("s_waitcnt vmcnt(4)" ::: "memory");                       \
    else if (ti_ == NTt - 2)                                                   \
        asm volatile("s_waitcnt vmcnt(0)" ::: "memory");                       \
    BAR();                                                                     \
  } while (0)

template <bool RELU_BF16_OUT, int MT, int NTILES, int K, int N>
__global__ __launch_bounds__(512, 2) void gemm8p(
    const ushort* __restrict__ A, const ushort* __restrict__ Bt,
    const float* __restrict__ bias, void* __restrict__ out) {
    __shared__ ushort smem[65536];          // 128 KiB
    constexpr int NTt = K / 64;             // K-tiles
    static_assert(K % 64 == 0 && (NTt % 2) == 0, "need even K-tile count");
    constexpr int STC = NTILES / 4;         // supertile columns

    // T1: pid%8 -> XCD; each XCD owns one expert (tiles/expert == nwg/8).
    const int pid = blockIdx.x;
    const int e   = pid & 7;
    const int idx = pid >> 3;
    const int s  = idx >> 4, wi = idx & 15; // 4x4 supertiles
    const int by = (s / STC) * 4 + (wi >> 2);
    const int bx = (s % STC) * 4 + (wi & 3);
    const int m0 = by * 256, n0 = bx * 256;

    const ushort* Ae = A  + (size_t)e * 4096 * K;
    const ushort* Be = Bt + (size_t)e * N * K;
    const float*  be = bias + (size_t)e * N;

    const int t    = threadIdx.x;
    const int w    = t >> 6, l = t & 63;
    const int wm   = w >> 2;                // wave_m in {0,1}
    const int wn   = w & 3;                 // wave_n in {0..3}
    const int lrow = l & 15, q = l >> 4;
    const int swz  = (lrow & 7) << 3;       // read-side XOR (elements)

    // staging geometry: thread slice i=0/1 -> row r, pre-inverse-swizzled col c
    const int r0s = w * 16 + (l >> 3);
    const int r1s = r0s + 8;
    const int c0s = ((l & 7) ^ (r0s & 7)) << 3;
    const int c1s = ((l & 7) ^ (r1s & 7)) << 3;
    const int d0  = w * 1024 + l * 8;       // linear LDS dest (elements)
    const int d1  = d0 + 512;

    const ushort* pa0 = Ae + (size_t)(m0 + r0s) * K + c0s;
    const ushort* pa1 = Ae + (size_t)(m0 + r1s) * K + c1s;
    const ushort* pb0 = Be + (size_t)(n0 + r0s) * K + c0s;
    const ushort* pb1 = Be + (size_t)(n0 + r1s) * K + c1s;

    // bias first + drain, so the vmem queue holds ONLY staging loads
    float bv[4];
#pragma unroll
    for (int nf = 0; nf < 4; ++nf) bv[nf] = be[n0 + wn * 64 + nf * 16 + lrow];
    asm volatile("s_waitcnt vmcnt(0)" ::: "memory");

    // prologue: A(0),B(0) + A(1); wait tile0 (8 loads), keep A(1) in flight
    STAGE(pa0, pa1, (size_t)0,       0,             0);   // A h0 t0
    STAGE(pa0, pa1, (size_t)128 * K, 8192,          0);   // A h1 t0
    STAGE(pb0, pb1, (size_t)0,       16384,         0);   // B h0 t0
    STAGE(pb0, pb1, (size_t)128 * K, 16384 + 8192,  0);   // B h1 t0
    STAGE(pa0, pa1, (size_t)0,       32768,         1);   // A h0 t1
    STAGE(pa0, pa1, (size_t)128 * K, 32768 + 8192,  1);   // A h1 t1
    asm volatile("s_waitcnt vmcnt(4)" ::: "memory");
    BAR();

    short8 aX[4][2], aY[4][2], b[2][2];
    f32x4 acc[8][4] = {};

    // prologue register read: tile0 a(0..3) -> aX (drained by P1's lgkmcnt(0))
#pragma unroll
    for (int mf = 0; mf < 4; ++mf)
#pragma unroll
        for (int kh = 0; kh < 2; ++kh)
            aX[mf][kh] = *(const short8*)
                &smem[wm * 8192 + (mf * 16 + lrow) * 64 +
                      ((kh * 32 + q * 8) ^ swz)];

    for (int tt = 0; tt < NTt; tt += 2) {
        TILE_BODY(tt,     aX, aY, 0);
        TILE_BODY(tt + 1, aY, aX, 1);
    }

    // epilogue: C/D layout col=lane&15, row=quad*4+reg [m89/m91 verified]
    const size_t obase = (size_t)e * 4096 * N;
#pragma unroll
    for (int mf = 0; mf < 8; ++mf) {
#pragma unroll
        for (int nf = 0; nf < 4; ++nf) {
            const int gn = n0 + wn * 64 + nf * 16 + lrow;
#pragma unroll
            for (int rr = 0; rr < 4; ++rr) {
                const int gm = m0 + wm * 128 + mf * 16 + q * 4 + rr;
                float v = acc[mf][nf][rr] + bv[nf];
                if (RELU_BF16_OUT) {
                    v = fmaxf(v, 0.f);
                    ((ushort*)out)[obase + (size_t)gm * N + gn] = f2bf_rne(v);
                } else {
                    ((float*)out)[obase + (size_t)gm * N + gn] = v;
                }
            }
        }
    }
}

extern "C" void kernel_launch(void* const* d_in, const int* in_sizes, int n_in,
                              void* d_out, int out_size, void* d_ws, size_t ws_size,
                              hipStream_t stream) {
    const int E = 8, C = 4096, M = 1024, H = 4096, O = 1024;
    const float* x  = (const float*)d_in[0];
    const float* w1 = (const float*)d_in[1];
    const float* b1 = (const float*)d_in[2];
    const float* w2 = (const float*)d_in[3];
    const float* b2 = (const float*)d_in[4];
    float* out = (float*)d_out;

    // workspace: [x_bf 67MB][w1t 67MB][y 268MB]; w2t aliases w1t (used after GEMM1)
    ushort* x_bf = (ushort*)d_ws;                       // E*C*M
    ushort* w1t  = x_bf + (size_t)E * C * M;            // E*H*M
    ushort* w2t  = w1t;                                 // E*O*H (alias, after GEMM1)
    ushort* y_bf = w1t + (size_t)E * M * H;             // E*C*H

    const long nx = (long)E * C * M;
    convert_bf16<<<(nx / 8 + 255) / 256, 256, 0, stream>>>(x, x_bf, nx);
    transpose_convert<<<dim3(H / 64, M / 64, E), 256, 0, stream>>>(w1, w1t, M, H);
    // GEMM1: [E,4096,1024] @ [E,4096,1024]^T -> y [E,4096,4096] bf16, relu+bias
    gemm8p<true, 16, 16, 1024, 4096><<<16 * 16 * 8, 512, 0, stream>>>(
        x_bf, w1t, b1, (void*)y_bf);
    transpose_convert<<<dim3(O / 64, H / 64, E), 256, 0, stream>>>(w2, w2t, H, O);
    // GEMM2: [E,4096,4096] @ [E,1024,4096]^T -> out [E,4096,1024] fp32, bias
    gemm8p<false, 16, 4, 4096, 1024><<<16 * 4 * 8, 512, 0, stream>>>(
        y_bf, w2t, b2, (void*)out);
}